// Round 16
// baseline (437.712 us; speedup 1.0000x reference)
//
#include <hip/hip_runtime.h>
#include <math.h>

#define BATCH  8192
#define EMBED  768
#define DIMD   512
#define MEDIM  64
#define NSTEP  10

typedef __bf16 bf16x8 __attribute__((ext_vector_type(8)));
typedef float  f32x4  __attribute__((ext_vector_type(4)));

// ---- async global->LDS, 16B/lane; LDS base wave-uniform, HW adds lane*16;
// ---- global source address is PER-LANE (enables gather / pre-swizzle) ----
__device__ __forceinline__ void load16_lds(const void* g, void* l)
{
    auto* gp = (__attribute__((address_space(1))) char*)(uintptr_t)g;
    auto* lp = (__attribute__((address_space(3))) char*)(unsigned int)(uintptr_t)l;
    __builtin_amdgcn_global_load_lds(gp, lp, 16, 0, 0);
}

#define WAITV(n) asm volatile("s_waitcnt vmcnt(" #n ")" ::: "memory")

#define BN 128
#define BK 32

// ---------------------------------------------------------------------------
// Unified bf16 MFMA GEMM — counted-vmcnt 3-buffer + fine interleave + T5.
// (verbatim r15 structure; used for scan + MLP)
// ---------------------------------------------------------------------------
template<int ACT, bool ADDEB, bool GATHER, int BMT>
__global__ __launch_bounds__(256)
void gemm_bf16(const __bf16* __restrict__ A, const __bf16* __restrict__ Bt,
               const float* __restrict__ bias, const __bf16* __restrict__ add,
               const __bf16* __restrict__ me, const int* __restrict__ moves,
               __bf16* __restrict__ C, int M, int N, int K)
{
    constexpr int NG = (BMT + BN) / 16;
    constexpr int AG = BMT / 16;
    constexpr int MR = BMT / 32;
    constexpr int NC = NG / 4;

    __shared__ __bf16 lds[3][(BMT + BN) * BK];

    const int nwg  = gridDim.x * gridDim.y;
    const int orig = blockIdx.y * gridDim.x + blockIdx.x;
    const int cpx  = nwg >> 3;
    const int swz  = (orig & 7) * cpx + (orig >> 3);
    const int bx   = swz % gridDim.x;
    const int by   = swz / gridDim.x;

    const int tid  = threadIdx.x;
    const int wave = tid >> 6;
    const int lane = tid & 63;
    const int row0 = by * BMT;
    const int col0 = bx * BN;

    const int wr = (wave >> 1) * (BMT / 2);
    const int wc = (wave & 1) * 64;
    const int fr = lane & 15;
    const int q  = lane >> 4;

    const int srow = lane >> 2;
    const int skk  = (((lane & 3) ^ ((lane >> 3) & 3)) * 8);

    int mv[2] = {0, 0};
    if (GATHER) {
#pragma unroll
        for (int ci = 0; ci < 2; ++ci)
            mv[ci] = moves[row0 + (ci * 4 + wave) * 16 + srow];
    }

    auto stage_one = [&](int buf, int k0, int ci) {
        const int c = ci * 4 + wave;
        const int r = c * 16 + srow;
        const __bf16* g;
        if (c < AG) {
            if (GATHER) {
                g = (k0 < DIMD)
                    ? (A  + (size_t)(row0 + r) * DIMD + k0 + skk)
                    : (me + (size_t)mv[ci] * MEDIM + (k0 - DIMD) + skk);
            } else {
                g = A + (size_t)(row0 + r) * K + k0 + skk;
            }
        } else {
            g = Bt + (size_t)(col0 + (r - BMT)) * K + k0 + skk;
        }
        load16_lds(g, &lds[buf][c * 512]);
    };
    auto stage = [&](int buf, int k0) {
#pragma unroll
        for (int ci = 0; ci < NC; ++ci) stage_one(buf, k0, ci);
    };

    auto frag = [&](const __bf16* base, int r) -> bf16x8 {
        return *(const bf16x8*)&base[r * 32 + ((q ^ ((r >> 1) & 3)) << 3)];
    };

    f32x4 acc[MR][4] = {};

    const int NT = K / BK;
    stage(0, 0);
    stage(1, BK);

    int rd = 0;
    for (int t = 0; t < NT; ++t) {
        if (t + 1 < NT) {
            if constexpr (NC == 4) WAITV(4); else WAITV(3);
        } else {
            WAITV(0);
        }
        __builtin_amdgcn_s_barrier();
        __builtin_amdgcn_sched_barrier(0);

        const bool dost = (t + 2 < NT);
        int wrb = rd + 2; if (wrb >= 3) wrb -= 3;
        const int k0s = (t + 2) * BK;

        const __bf16* As = lds[rd];
        const __bf16* Bs = lds[rd] + BMT * BK;
        bf16x8 bfr[4];
#pragma unroll
        for (int n = 0; n < 4; ++n)
            bfr[n] = frag(Bs, wc + n * 16 + fr);

        __builtin_amdgcn_s_setprio(1);
#pragma unroll
        for (int m = 0; m < MR; ++m) {
            if (dost) {
#pragma unroll
                for (int ci = m * NC / MR; ci < (m + 1) * NC / MR; ++ci)
                    stage_one(wrb, k0s, ci);
            }
            const bf16x8 af = frag(As, wr + m * 16 + fr);
#pragma unroll
            for (int n = 0; n < 4; ++n)
                acc[m][n] = __builtin_amdgcn_mfma_f32_16x16x32_bf16(
                                af, bfr[n], acc[m][n], 0, 0, 0);
        }
        __builtin_amdgcn_s_setprio(0);

        __builtin_amdgcn_s_barrier();
        __builtin_amdgcn_sched_barrier(0);
        ++rd; if (rd >= 3) rd -= 3;
    }

#pragma unroll
    for (int m = 0; m < MR; ++m) {
#pragma unroll
        for (int n = 0; n < 4; ++n) {
            const int cc = col0 + wc + n * 16 + fr;
            const float bb = bias[cc];
#pragma unroll
            for (int j = 0; j < 4; ++j) {
                const int rr = row0 + wr + m * 16 + (lane >> 4) * 4 + j;
                float v = acc[m][n][j] + bb;
                if (ADDEB) v += (float)add[(size_t)rr * N + cc];
                if (ACT == 1) v = fmaxf(v, 0.0f);
                if (ACT == 2) {
                    const float p = __expf(2.0f * v);
                    v = 1.0f - 2.0f / (p + 1.0f);
                }
                C[(size_t)rr * N + cc] = (__bf16)v;
            }
        }
    }
}

// ---------------------------------------------------------------------------
// 256x128 tile, 512 threads, 8 waves (4M x 2N) — per-wave 64x64 (the verified
// fragment geometry), same r15 schedule. 192 B staged per MFMA (-25% vs 128²).
// 3 x 24 KB LDS -> 2 blocks/CU. For the two M=81920 GEMMs (reducer, eb).
// H1: rows < BATCH are step-0 rows of eb -> write tanh(tmp+v) into h1out
// instead of C (eb0's only consumer was h1_init — now fused).
// ---------------------------------------------------------------------------
template<int ACT, bool H1>
__global__ __launch_bounds__(512)
void gemm256(const __bf16* __restrict__ A, const __bf16* __restrict__ Bt,
             const float* __restrict__ bias, const float* __restrict__ tmp,
             __bf16* __restrict__ h1out, __bf16* __restrict__ C,
             int M, int N, int K)
{
    __shared__ __bf16 lds[3][(256 + 128) * 32];   // 3 x 24 KB

    const int nwg  = gridDim.x * gridDim.y;
    const int orig = blockIdx.y * gridDim.x + blockIdx.x;
    const int cpx  = nwg >> 3;
    const int swz  = (orig & 7) * cpx + (orig >> 3);
    const int bx   = swz % gridDim.x;
    const int by   = swz / gridDim.x;

    const int tid  = threadIdx.x;
    const int wave = tid >> 6;        // 0..7
    const int lane = tid & 63;
    const int row0 = by * 256;
    const int col0 = bx * 128;

    const int wr = (wave >> 1) * 64;  // 4 M-positions
    const int wc = (wave & 1) * 64;   // 2 N-positions
    const int fr = lane & 15;
    const int q  = lane >> 4;

    const int srow = lane >> 2;
    const int skk  = (((lane & 3) ^ ((lane >> 3) & 3)) * 8);

    // 24 groups of 16 rows (A: 0..15, B: 16..23), NC=3 per wave
    auto stage_one = [&](int buf, int k0, int ci) {
        const int c = ci * 8 + wave;
        const int r = c * 16 + srow;
        const __bf16* g = (c < 16)
            ? (A  + (size_t)(row0 + r) * K + k0 + skk)
            : (Bt + (size_t)(col0 + (r - 256)) * K + k0 + skk);
        load16_lds(g, &lds[buf][c * 512]);
    };
    auto stage = [&](int buf, int k0) {
#pragma unroll
        for (int ci = 0; ci < 3; ++ci) stage_one(buf, k0, ci);
    };

    auto frag = [&](const __bf16* base, int r) -> bf16x8 {
        return *(const bf16x8*)&base[r * 32 + ((q ^ ((r >> 1) & 3)) << 3)];
    };

    f32x4 acc[4][4] = {};

    const int NT = K / BK;
    stage(0, 0);
    stage(1, BK);

    int rd = 0;
    for (int t = 0; t < NT; ++t) {
        if (t + 1 < NT) WAITV(3); else WAITV(0);
        __builtin_amdgcn_s_barrier();
        __builtin_amdgcn_sched_barrier(0);

        const bool dost = (t + 2 < NT);
        int wrb = rd + 2; if (wrb >= 3) wrb -= 3;
        const int k0s = (t + 2) * BK;

        const __bf16* As = lds[rd];
        const __bf16* Bs = lds[rd] + 256 * 32;
        bf16x8 bfr[4];
#pragma unroll
        for (int n = 0; n < 4; ++n)
            bfr[n] = frag(Bs, wc + n * 16 + fr);

        __builtin_amdgcn_s_setprio(1);
#pragma unroll
        for (int m = 0; m < 4; ++m) {
            if (dost) {
#pragma unroll
                for (int ci = m * 3 / 4; ci < (m + 1) * 3 / 4; ++ci)
                    stage_one(wrb, k0s, ci);
            }
            const bf16x8 af = frag(As, wr + m * 16 + fr);
#pragma unroll
            for (int n = 0; n < 4; ++n)
                acc[m][n] = __builtin_amdgcn_mfma_f32_16x16x32_bf16(
                                af, bfr[n], acc[m][n], 0, 0, 0);
        }
        __builtin_amdgcn_s_setprio(0);

        __builtin_amdgcn_s_barrier();
        __builtin_amdgcn_sched_barrier(0);
        ++rd; if (rd >= 3) rd -= 3;
    }

#pragma unroll
    for (int m = 0; m < 4; ++m) {
#pragma unroll
        for (int n = 0; n < 4; ++n) {
            const int cc = col0 + wc + n * 16 + fr;
            const float bb = bias[cc];
#pragma unroll
            for (int j = 0; j < 4; ++j) {
                const int rr = row0 + wr + m * 16 + (lane >> 4) * 4 + j;
                float v = acc[m][n][j] + bb;
                if (ACT == 1) v = fmaxf(v, 0.0f);
                if (H1 && rr < BATCH) {
                    const float vv = v + tmp[cc];
                    const float p = __expf(2.0f * vv);
                    h1out[(size_t)rr * N + cc] = (__bf16)(1.0f - 2.0f / (p + 1.0f));
                } else {
                    C[(size_t)rr * N + cc] = (__bf16)v;
                }
            }
        }
    }
}

// ---- weight-pool segment table ----
enum : int { W_RED = 0, W_CA = 393216, W_CB = 655360, W_FC1 = 917504,
             W_FC2 = 1212416, W_FC3 = 1474560, W_FC4 = 1998848,
             W_FC5 = 3047424, W_ME = 3571712, W_TOTAL = 3575808 };

// ---------------------------------------------------------------------------
// Fused prep: boards cvt+mask; weights cvt; gemv_start.
// ---------------------------------------------------------------------------
#define NB_BOARDS 30720
#define NB_W      1746
__global__ __launch_bounds__(256)
void prep(const float* __restrict__ boards, const int* __restrict__ flags,
          __bf16* __restrict__ b_all,
          const float* __restrict__ w0, const float* __restrict__ w1,
          const float* __restrict__ w2, const float* __restrict__ w3,
          const float* __restrict__ w4, const float* __restrict__ w5,
          const float* __restrict__ w6, const float* __restrict__ w7,
          const float* __restrict__ w8, __bf16* __restrict__ wpool,
          const float* __restrict__ cab, const float* __restrict__ start,
          float* __restrict__ tmp)
{
    const int bid = blockIdx.x;
    if (bid < NB_BOARDS) {
        const int idx  = bid * 256 + threadIdx.x;
        const int grow = idx / 96;
        const int s    = grow >> 13;
        const int b    = grow & 8191;
        float m = 1.0f;
        if (s >= 2) m = flags[(size_t)(s - 2) * BATCH + b] ? 1.0f : 0.0f;
        const float4 v0 = ((const float4*)boards)[(size_t)idx * 2];
        const float4 v1 = ((const float4*)boards)[(size_t)idx * 2 + 1];
        bf16x8 o;
        o[0] = (__bf16)(v0.x * m); o[1] = (__bf16)(v0.y * m);
        o[2] = (__bf16)(v0.z * m); o[3] = (__bf16)(v0.w * m);
        o[4] = (__bf16)(v1.x * m); o[5] = (__bf16)(v1.y * m);
        o[6] = (__bf16)(v1.z * m); o[7] = (__bf16)(v1.w * m);
        *(bf16x8*)(b_all + (size_t)idx * 8) = o;
    } else if (bid < NB_BOARDS + NB_W) {
        const int idx = (bid - NB_BOARDS) * 256 + threadIdx.x;
        if (idx >= W_TOTAL / 8) return;
        const int e = idx * 8;
        const float* src; int off;
        if      (e < W_CA)  { src = w0; off = W_RED; }
        else if (e < W_CB)  { src = w1; off = W_CA; }
        else if (e < W_FC1) { src = w2; off = W_CB; }
        else if (e < W_FC2) { src = w3; off = W_FC1; }
        else if (e < W_FC3) { src = w4; off = W_FC2; }
        else if (e < W_FC4) { src = w5; off = W_FC3; }
        else if (e < W_FC5) { src = w6; off = W_FC4; }
        else if (e < W_ME)  { src = w7; off = W_FC5; }
        else                { src = w8; off = W_ME; }
        const float4 v0 = ((const float4*)(src + (e - off)))[0];
        const float4 v1 = ((const float4*)(src + (e - off)))[1];
        bf16x8 o;
        o[0] = (__bf16)v0.x; o[1] = (__bf16)v0.y; o[2] = (__bf16)v0.z; o[3] = (__bf16)v0.w;
        o[4] = (__bf16)v1.x; o[5] = (__bf16)v1.y; o[6] = (__bf16)v1.z; o[7] = (__bf16)v1.w;
        *(bf16x8*)(wpool + (size_t)e) = o;
    } else {
        __shared__ float s[DIMD];
        for (int i = threadIdx.x; i < DIMD; i += 256) s[i] = start[i];
        __syncthreads();
        const int n = (bid - NB_BOARDS - NB_W) * 256 + threadIdx.x;
        const float4* w = (const float4*)(w1 + (size_t)n * DIMD);    // w1 = ca_w
        float acc = 0.0f;
#pragma unroll 8
        for (int k = 0; k < DIMD / 4; ++k) {
            const float4 wv = w[k];
            acc += wv.x * s[k * 4] + wv.y * s[k * 4 + 1] +
                   wv.z * s[k * 4 + 2] + wv.w * s[k * 4 + 3];
        }
        tmp[n] = acc + cab[n];
    }
}

// ---- out[b] = dot(x5[b,:512], out_w) + out_b ----
__global__ __launch_bounds__(256)
void out_head(const __bf16* __restrict__ x, const float* __restrict__ out_w,
              const float* __restrict__ out_b, float* __restrict__ out)
{
    const int wid  = threadIdx.x >> 6;
    const int lane = threadIdx.x & 63;
    const int row  = blockIdx.x * 4 + wid;
    const bf16x8 xv = *(const bf16x8*)(x + (size_t)row * DIMD + lane * 8);
    const float4 w0 = ((const float4*)out_w)[lane * 2];
    const float4 w1 = ((const float4*)out_w)[lane * 2 + 1];
    float s = (float)xv[0] * w0.x + (float)xv[1] * w0.y + (float)xv[2] * w0.z +
              (float)xv[3] * w0.w + (float)xv[4] * w1.x + (float)xv[5] * w1.y +
              (float)xv[6] * w1.z + (float)xv[7] * w1.w;
#pragma unroll
    for (int off = 32; off; off >>= 1) s += __shfl_down(s, off, 64);
    if (lane == 0) out[row] = s + out_b[0];
}

extern "C" void kernel_launch(void* const* d_in, const int* in_sizes, int n_in,
                              void* d_out, int out_size, void* d_ws, size_t ws_size,
                              hipStream_t stream)
{
    const float* boards  = (const float*)d_in[0];
    const int*   flags   = (const int*)  d_in[1];
    const int*   moves   = (const int*)  d_in[3];
    const float* start   = (const float*)d_in[4];
    const float* red_w   = (const float*)d_in[5];
    const float* red_b   = (const float*)d_in[6];
    const float* ca_w    = (const float*)d_in[7];
    const float* ca_b    = (const float*)d_in[8];
    const float* cb_w    = (const float*)d_in[9];
    const float* cb_b    = (const float*)d_in[10];
    const float* move_emb= (const float*)d_in[11];
    const float* fc1_w   = (const float*)d_in[12];
    const float* fc1_b   = (const float*)d_in[13];
    const float* fc2_w   = (const float*)d_in[14];
    const float* fc2_b   = (const float*)d_in[15];
    const float* fc3_w   = (const float*)d_in[16];
    const float* fc3_b   = (const float*)d_in[17];
    const float* fc4_w   = (const float*)d_in[18];
    const float* fc4_b   = (const float*)d_in[19];
    const float* fc5_w   = (const float*)d_in[20];
    const float* fc5_b   = (const float*)d_in[21];
    const float* out_w   = (const float*)d_in[22];
    const float* out_b   = (const float*)d_in[23];

    __bf16* wsb = (__bf16*)d_ws;
    __bf16* wpool  = wsb;                          //   3,575,808
    __bf16* b_all  = wsb + 3575808;                //  62,914,560  [81920][768]
    __bf16* e_all  = wsb + 66490368;               //  41,943,040  [81920][512]
    __bf16* eb_all = wsb + 108433408;              //  41,943,040
    __bf16* hA     = wsb + 150376448;              //   4,194,304
    __bf16* hB     = wsb + 154570752;              //   4,194,304
    float*  tmpv   = (float*)(wsb + 158765056);    //   512 f32
    __bf16* x1     = wsb + 159789056;              //   4,194,304
    __bf16* x2     = wsb + 163983360;              //   4,194,304
    __bf16* x3     = wsb + 168177664;              //   8,388,608
    __bf16* x4     = wsb + 176566272;              //   8,388,608
    __bf16* x5     = wsb + 184954880;              //   4,194,304

    const dim3 blk(256);

    // fused prep: boards cvt+mask, weights cvt, start gemv
    prep<<<NB_BOARDS + NB_W + 2, blk, 0, stream>>>(
        boards, flags, b_all,
        red_w, ca_w, cb_w, fc1_w, fc2_w, fc3_w, fc4_w, fc5_w, move_emb, wpool,
        ca_b, start, tmpv);

    // batched reducer: e_all = relu(b_all @ red_w^T + red_b), 256x128 tile
    gemm256<1, false><<<dim3(4, 320), dim3(512), 0, stream>>>(
        b_all, wpool + W_RED, red_b, nullptr, nullptr, e_all,
        NSTEP * BATCH, DIMD, EMBED);
    // batched eb (+ fused h1 for step-0 rows): eb_all = e_all @ cb_w^T + cb_b
    gemm256<0, true><<<dim3(4, 320), dim3(512), 0, stream>>>(
        e_all, wpool + W_CB, cb_b, tmpv, hA, eb_all,
        NSTEP * BATCH, DIMD, DIMD);

    // steps 1..9: h = tanh(h @ ca_w^T + ca_b + eb_s); BM=64 -> 512 blocks
    __bf16* hcur = hA;
    __bf16* hnxt = hB;
    for (int s = 1; s < NSTEP; ++s) {
        const __bf16* ebs = eb_all + (size_t)s * BATCH * DIMD;
        gemm_bf16<2, true, false, 64><<<dim3(4, 128), blk, 0, stream>>>(
            hcur, wpool + W_CA, ca_b, ebs, nullptr, nullptr, hnxt,
            BATCH, DIMD, DIMD);
        __bf16* t = hcur; hcur = hnxt; hnxt = t;
    }

    // MLP at BMT=128 (r15 config)
    gemm_bf16<1, false, true, 128><<<dim3(4, 64), blk, 0, stream>>>(
        hcur, wpool + W_FC1, fc1_b, nullptr, wpool + W_ME, moves, x1,
        BATCH, DIMD, DIMD + MEDIM);
    gemm_bf16<1, false, false, 128><<<dim3(4, 64), blk, 0, stream>>>(
        x1, wpool + W_FC2, fc2_b, nullptr, nullptr, nullptr, x2, BATCH, DIMD, DIMD);
    gemm_bf16<1, false, false, 128><<<dim3(8, 64), blk, 0, stream>>>(
        x2, wpool + W_FC3, fc3_b, nullptr, nullptr, nullptr, x3, BATCH, 1024, DIMD);
    gemm_bf16<1, false, false, 128><<<dim3(8, 64), blk, 0, stream>>>(
        x3, wpool + W_FC4, fc4_b, nullptr, nullptr, nullptr, x4, BATCH, 1024, 1024);
    gemm_bf16<1, false, false, 128><<<dim3(4, 64), blk, 0, stream>>>(
        x4, wpool + W_FC5, fc5_b, nullptr, nullptr, nullptr, x5, BATCH, DIMD, 1024);

    out_head<<<BATCH / 4, blk, 0, stream>>>(x5, out_w, out_b, (float*)d_out);
}

// Round 17
// 436.017 us; speedup vs baseline: 1.0039x; 1.0039x over previous
//
#include <hip/hip_runtime.h>
#include <math.h>

#define BATCH  8192
#define EMBED  768
#define DIMD   512
#define MEDIM  64
#define NSTEP  10

typedef __bf16 bf16x8 __attribute__((ext_vector_type(8)));
typedef float  f32x4  __attribute__((ext_vector_type(4)));

// ---- async global->LDS, 16B/lane; LDS base wave-uniform, HW adds lane*16;
// ---- global source address is PER-LANE (enables gather / pre-swizzle) ----
__device__ __forceinline__ void load16_lds(const void* g, void* l)
{
    auto* gp = (__attribute__((address_space(1))) char*)(uintptr_t)g;
    auto* lp = (__attribute__((address_space(3))) char*)(unsigned int)(uintptr_t)l;
    __builtin_amdgcn_global_load_lds(gp, lp, 16, 0, 0);
}

#define WAITV(n) asm volatile("s_waitcnt vmcnt(" #n ")" ::: "memory")

#define BN 128
#define BK 32

// ---------------------------------------------------------------------------
// Unified bf16 MFMA GEMM — counted-vmcnt 3-buffer + fine interleave + T5.
// (verbatim r15 structure; used for scan + MLP)
// ---------------------------------------------------------------------------
template<int ACT, bool ADDEB, bool GATHER, int BMT>
__global__ __launch_bounds__(256)
void gemm_bf16(const __bf16* __restrict__ A, const __bf16* __restrict__ Bt,
               const float* __restrict__ bias, const __bf16* __restrict__ add,
               const __bf16* __restrict__ me, const int* __restrict__ moves,
               __bf16* __restrict__ C, int M, int N, int K)
{
    constexpr int NG = (BMT + BN) / 16;
    constexpr int AG = BMT / 16;
    constexpr int MR = BMT / 32;
    constexpr int NC = NG / 4;

    __shared__ __bf16 lds[3][(BMT + BN) * BK];

    const int nwg  = gridDim.x * gridDim.y;
    const int orig = blockIdx.y * gridDim.x + blockIdx.x;
    const int cpx  = nwg >> 3;
    const int swz  = (orig & 7) * cpx + (orig >> 3);
    const int bx   = swz % gridDim.x;
    const int by   = swz / gridDim.x;

    const int tid  = threadIdx.x;
    const int wave = tid >> 6;
    const int lane = tid & 63;
    const int row0 = by * BMT;
    const int col0 = bx * BN;

    const int wr = (wave >> 1) * (BMT / 2);
    const int wc = (wave & 1) * 64;
    const int fr = lane & 15;
    const int q  = lane >> 4;

    const int srow = lane >> 2;
    const int skk  = (((lane & 3) ^ ((lane >> 3) & 3)) * 8);

    int mv[2] = {0, 0};
    if (GATHER) {
#pragma unroll
        for (int ci = 0; ci < 2; ++ci)
            mv[ci] = moves[row0 + (ci * 4 + wave) * 16 + srow];
    }

    auto stage_one = [&](int buf, int k0, int ci) {
        const int c = ci * 4 + wave;
        const int r = c * 16 + srow;
        const __bf16* g;
        if (c < AG) {
            if (GATHER) {
                g = (k0 < DIMD)
                    ? (A  + (size_t)(row0 + r) * DIMD + k0 + skk)
                    : (me + (size_t)mv[ci] * MEDIM + (k0 - DIMD) + skk);
            } else {
                g = A + (size_t)(row0 + r) * K + k0 + skk;
            }
        } else {
            g = Bt + (size_t)(col0 + (r - BMT)) * K + k0 + skk;
        }
        load16_lds(g, &lds[buf][c * 512]);
    };
    auto stage = [&](int buf, int k0) {
#pragma unroll
        for (int ci = 0; ci < NC; ++ci) stage_one(buf, k0, ci);
    };

    auto frag = [&](const __bf16* base, int r) -> bf16x8 {
        return *(const bf16x8*)&base[r * 32 + ((q ^ ((r >> 1) & 3)) << 3)];
    };

    f32x4 acc[MR][4] = {};

    const int NT = K / BK;
    stage(0, 0);
    stage(1, BK);

    int rd = 0;
    for (int t = 0; t < NT; ++t) {
        if (t + 1 < NT) {
            if constexpr (NC == 4) WAITV(4); else WAITV(3);
        } else {
            WAITV(0);
        }
        __builtin_amdgcn_s_barrier();
        __builtin_amdgcn_sched_barrier(0);

        const bool dost = (t + 2 < NT);
        int wrb = rd + 2; if (wrb >= 3) wrb -= 3;
        const int k0s = (t + 2) * BK;

        const __bf16* As = lds[rd];
        const __bf16* Bs = lds[rd] + BMT * BK;
        bf16x8 bfr[4];
#pragma unroll
        for (int n = 0; n < 4; ++n)
            bfr[n] = frag(Bs, wc + n * 16 + fr);

        __builtin_amdgcn_s_setprio(1);
#pragma unroll
        for (int m = 0; m < MR; ++m) {
            if (dost) {
#pragma unroll
                for (int ci = m * NC / MR; ci < (m + 1) * NC / MR; ++ci)
                    stage_one(wrb, k0s, ci);
            }
            const bf16x8 af = frag(As, wr + m * 16 + fr);
#pragma unroll
            for (int n = 0; n < 4; ++n)
                acc[m][n] = __builtin_amdgcn_mfma_f32_16x16x32_bf16(
                                af, bfr[n], acc[m][n], 0, 0, 0);
        }
        __builtin_amdgcn_s_setprio(0);

        __builtin_amdgcn_s_barrier();
        __builtin_amdgcn_sched_barrier(0);
        ++rd; if (rd >= 3) rd -= 3;
    }

#pragma unroll
    for (int m = 0; m < MR; ++m) {
#pragma unroll
        for (int n = 0; n < 4; ++n) {
            const int cc = col0 + wc + n * 16 + fr;
            const float bb = bias[cc];
#pragma unroll
            for (int j = 0; j < 4; ++j) {
                const int rr = row0 + wr + m * 16 + (lane >> 4) * 4 + j;
                float v = acc[m][n][j] + bb;
                if (ADDEB) v += (float)add[(size_t)rr * N + cc];
                if (ACT == 1) v = fmaxf(v, 0.0f);
                if (ACT == 2) {
                    const float p = __expf(2.0f * v);
                    v = 1.0f - 2.0f / (p + 1.0f);
                }
                C[(size_t)rr * N + cc] = (__bf16)v;
            }
        }
    }
}

// ---------------------------------------------------------------------------
// 8-phase-style 256x256 GEMM (reducer): 512 thr, 8 waves (2M x 4N),
// per-wave 128x64 = acc[8][4]. BK=32, 3 x 32KB dynamic LDS (1 blk/CU).
// Per K-iter: WAITV(4) [stage(t) issued 2 iters back]; barrier; then 4 phases
// {1 stage call for t+2 ; 2 af reads ; setprio(1); 8 MFMA; setprio(0);
//  barrier}. Per-phase barriers create wave role-diversity (T3 mechanism);
// counted vmcnt never 0 mid-loop (T4). Buffer safety: stage(t+2) writes the
// buffer of tile t-1, whose reads ended at iter t-1's last phase barrier.
// ---------------------------------------------------------------------------
template<int ACT>
__global__ __launch_bounds__(512)
void gemm8p(const __bf16* __restrict__ A, const __bf16* __restrict__ Bt,
            const float* __restrict__ bias, __bf16* __restrict__ C,
            int M, int N, int K)
{
    extern __shared__ __bf16 dyn[];           // 3 x 16384 elems (3 x 32 KB)

    const int nwg  = gridDim.x * gridDim.y;
    const int orig = blockIdx.y * gridDim.x + blockIdx.x;
    const int cpx  = nwg >> 3;
    const int swz  = (orig & 7) * cpx + (orig >> 3);
    const int bx   = swz % gridDim.x;
    const int by   = swz / gridDim.x;

    const int tid  = threadIdx.x;
    const int wave = tid >> 6;                // 0..7
    const int lane = tid & 63;
    const int row0 = by * 256;
    const int col0 = bx * 256;

    const int wr = (wave >> 2) * 128;         // 2 M-waves
    const int wc = (wave & 3) * 64;           // 4 N-waves
    const int fr = lane & 15;
    const int q  = lane >> 4;

    const int srow = lane >> 2;
    const int skk  = (((lane & 3) ^ ((lane >> 3) & 3)) * 8);

    // 32 groups of 16 rows per k-step (A: 0..15, B: 16..31), 4 calls/wave
    auto stage_one = [&](int buf, int k0, int ci) {
        const int c = ci * 8 + wave;
        const int r = c * 16 + srow;
        const __bf16* g = (c < 16)
            ? (A  + (size_t)(row0 + r) * K + k0 + skk)
            : (Bt + (size_t)(col0 + (r - 256)) * K + k0 + skk);
        load16_lds(g, &dyn[buf * 16384 + c * 512]);
    };
    auto stage = [&](int buf, int k0) {
#pragma unroll
        for (int ci = 0; ci < 4; ++ci) stage_one(buf, k0, ci);
    };

    auto frag = [&](const __bf16* base, int r) -> bf16x8 {
        return *(const bf16x8*)&base[r * 32 + ((q ^ ((r >> 1) & 3)) << 3)];
    };

    f32x4 acc[8][4] = {};

    const int NT = K / BK;
    stage(0, 0);
    stage(1, BK);

    int rd = 0;
    for (int t = 0; t < NT; ++t) {
        if (t + 1 < NT) WAITV(4); else WAITV(0);
        __builtin_amdgcn_s_barrier();
        __builtin_amdgcn_sched_barrier(0);

        const bool dost = (t + 2 < NT);
        int wrb = rd + 2; if (wrb >= 3) wrb -= 3;
        const int k0s = (t + 2) * BK;

        const __bf16* As = dyn + rd * 16384;
        const __bf16* Bs = As + 256 * 32;
        bf16x8 bfr[4];
#pragma unroll
        for (int n = 0; n < 4; ++n)
            bfr[n] = frag(Bs, wc + n * 16 + fr);

        // 4 phases: each stages 1 call for tile t+2, computes 2 m-frags x 4 n
#pragma unroll
        for (int p = 0; p < 4; ++p) {
            if (dost) stage_one(wrb, k0s, p);
            const bf16x8 af0 = frag(As, wr + (2 * p)     * 16 + fr);
            const bf16x8 af1 = frag(As, wr + (2 * p + 1) * 16 + fr);
            __builtin_amdgcn_s_setprio(1);
#pragma unroll
            for (int n = 0; n < 4; ++n)
                acc[2 * p][n] = __builtin_amdgcn_mfma_f32_16x16x32_bf16(
                                    af0, bfr[n], acc[2 * p][n], 0, 0, 0);
#pragma unroll
            for (int n = 0; n < 4; ++n)
                acc[2 * p + 1][n] = __builtin_amdgcn_mfma_f32_16x16x32_bf16(
                                        af1, bfr[n], acc[2 * p + 1][n], 0, 0, 0);
            __builtin_amdgcn_s_setprio(0);
            __builtin_amdgcn_s_barrier();
            __builtin_amdgcn_sched_barrier(0);
        }
        ++rd; if (rd >= 3) rd -= 3;
    }

#pragma unroll
    for (int m = 0; m < 8; ++m) {
#pragma unroll
        for (int n = 0; n < 4; ++n) {
            const int cc = col0 + wc + n * 16 + fr;
            const float bb = bias[cc];
#pragma unroll
            for (int j = 0; j < 4; ++j) {
                const int rr = row0 + wr + m * 16 + (lane >> 4) * 4 + j;
                float v = acc[m][n][j] + bb;
                if (ACT == 1) v = fmaxf(v, 0.0f);
                C[(size_t)rr * N + cc] = (__bf16)v;
            }
        }
    }
}

// ---------------------------------------------------------------------------
// 256x128 tile, 512 threads, 8 waves (4M x 2N) — r16 kernel (used for eb+h1).
// ---------------------------------------------------------------------------
template<int ACT, bool H1>
__global__ __launch_bounds__(512)
void gemm256(const __bf16* __restrict__ A, const __bf16* __restrict__ Bt,
             const float* __restrict__ bias, const float* __restrict__ tmp,
             __bf16* __restrict__ h1out, __bf16* __restrict__ C,
             int M, int N, int K)
{
    __shared__ __bf16 lds[3][(256 + 128) * 32];   // 3 x 24 KB

    const int nwg  = gridDim.x * gridDim.y;
    const int orig = blockIdx.y * gridDim.x + blockIdx.x;
    const int cpx  = nwg >> 3;
    const int swz  = (orig & 7) * cpx + (orig >> 3);
    const int bx   = swz % gridDim.x;
    const int by   = swz / gridDim.x;

    const int tid  = threadIdx.x;
    const int wave = tid >> 6;        // 0..7
    const int lane = tid & 63;
    const int row0 = by * 256;
    const int col0 = bx * 128;

    const int wr = (wave >> 1) * 64;  // 4 M-positions
    const int wc = (wave & 1) * 64;   // 2 N-positions
    const int fr = lane & 15;
    const int q  = lane >> 4;

    const int srow = lane >> 2;
    const int skk  = (((lane & 3) ^ ((lane >> 3) & 3)) * 8);

    auto stage_one = [&](int buf, int k0, int ci) {
        const int c = ci * 8 + wave;
        const int r = c * 16 + srow;
        const __bf16* g = (c < 16)
            ? (A  + (size_t)(row0 + r) * K + k0 + skk)
            : (Bt + (size_t)(col0 + (r - 256)) * K + k0 + skk);
        load16_lds(g, &lds[buf][c * 512]);
    };
    auto stage = [&](int buf, int k0) {
#pragma unroll
        for (int ci = 0; ci < 3; ++ci) stage_one(buf, k0, ci);
    };

    auto frag = [&](const __bf16* base, int r) -> bf16x8 {
        return *(const bf16x8*)&base[r * 32 + ((q ^ ((r >> 1) & 3)) << 3)];
    };

    f32x4 acc[4][4] = {};

    const int NT = K / BK;
    stage(0, 0);
    stage(1, BK);

    int rd = 0;
    for (int t = 0; t < NT; ++t) {
        if (t + 1 < NT) WAITV(3); else WAITV(0);
        __builtin_amdgcn_s_barrier();
        __builtin_amdgcn_sched_barrier(0);

        const bool dost = (t + 2 < NT);
        int wrb = rd + 2; if (wrb >= 3) wrb -= 3;
        const int k0s = (t + 2) * BK;

        const __bf16* As = lds[rd];
        const __bf16* Bs = lds[rd] + 256 * 32;
        bf16x8 bfr[4];
#pragma unroll
        for (int n = 0; n < 4; ++n)
            bfr[n] = frag(Bs, wc + n * 16 + fr);

        __builtin_amdgcn_s_setprio(1);
#pragma unroll
        for (int m = 0; m < 4; ++m) {
            if (dost) {
#pragma unroll
                for (int ci = m * 3 / 4; ci < (m + 1) * 3 / 4; ++ci)
                    stage_one(wrb, k0s, ci);
            }
            const bf16x8 af = frag(As, wr + m * 16 + fr);
#pragma unroll
            for (int n = 0; n < 4; ++n)
                acc[m][n] = __builtin_amdgcn_mfma_f32_16x16x32_bf16(
                                af, bfr[n], acc[m][n], 0, 0, 0);
        }
        __builtin_amdgcn_s_setprio(0);

        __builtin_amdgcn_s_barrier();
        __builtin_amdgcn_sched_barrier(0);
        ++rd; if (rd >= 3) rd -= 3;
    }

#pragma unroll
    for (int m = 0; m < 4; ++m) {
#pragma unroll
        for (int n = 0; n < 4; ++n) {
            const int cc = col0 + wc + n * 16 + fr;
            const float bb = bias[cc];
#pragma unroll
            for (int j = 0; j < 4; ++j) {
                const int rr = row0 + wr + m * 16 + (lane >> 4) * 4 + j;
                float v = acc[m][n][j] + bb;
                if (ACT == 1) v = fmaxf(v, 0.0f);
                if (H1 && rr < BATCH) {
                    const float vv = v + tmp[cc];
                    const float p = __expf(2.0f * vv);
                    h1out[(size_t)rr * N + cc] = (__bf16)(1.0f - 2.0f / (p + 1.0f));
                } else {
                    C[(size_t)rr * N + cc] = (__bf16)v;
                }
            }
        }
    }
}

// ---- weight-pool segment table ----
enum : int { W_RED = 0, W_CA = 393216, W_CB = 655360, W_FC1 = 917504,
             W_FC2 = 1212416, W_FC3 = 1474560, W_FC4 = 1998848,
             W_FC5 = 3047424, W_ME = 3571712, W_TOTAL = 3575808 };

// ---------------------------------------------------------------------------
// Fused prep: boards cvt+mask; weights cvt; gemv_start.
// ---------------------------------------------------------------------------
#define NB_BOARDS 30720
#define NB_W      1746
__global__ __launch_bounds__(256)
void prep(const float* __restrict__ boards, const int* __restrict__ flags,
          __bf16* __restrict__ b_all,
          const float* __restrict__ w0, const float* __restrict__ w1,
          const float* __restrict__ w2, const float* __restrict__ w3,
          const float* __restrict__ w4, const float* __restrict__ w5,
          const float* __restrict__ w6, const float* __restrict__ w7,
          const float* __restrict__ w8, __bf16* __restrict__ wpool,
          const float* __restrict__ cab, const float* __restrict__ start,
          float* __restrict__ tmp)
{
    const int bid = blockIdx.x;
    if (bid < NB_BOARDS) {
        const int idx  = bid * 256 + threadIdx.x;
        const int grow = idx / 96;
        const int s    = grow >> 13;
        const int b    = grow & 8191;
        float m = 1.0f;
        if (s >= 2) m = flags[(size_t)(s - 2) * BATCH + b] ? 1.0f : 0.0f;
        const float4 v0 = ((const float4*)boards)[(size_t)idx * 2];
        const float4 v1 = ((const float4*)boards)[(size_t)idx * 2 + 1];
        bf16x8 o;
        o[0] = (__bf16)(v0.x * m); o[1] = (__bf16)(v0.y * m);
        o[2] = (__bf16)(v0.z * m); o[3] = (__bf16)(v0.w * m);
        o[4] = (__bf16)(v1.x * m); o[5] = (__bf16)(v1.y * m);
        o[6] = (__bf16)(v1.z * m); o[7] = (__bf16)(v1.w * m);
        *(bf16x8*)(b_all + (size_t)idx * 8) = o;
    } else if (bid < NB_BOARDS + NB_W) {
        const int idx = (bid - NB_BOARDS) * 256 + threadIdx.x;
        if (idx >= W_TOTAL / 8) return;
        const int e = idx * 8;
        const float* src; int off;
        if      (e < W_CA)  { src = w0; off = W_RED; }
        else if (e < W_CB)  { src = w1; off = W_CA; }
        else if (e < W_FC1) { src = w2; off = W_CB; }
        else if (e < W_FC2) { src = w3; off = W_FC1; }
        else if (e < W_FC3) { src = w4; off = W_FC2; }
        else if (e < W_FC4) { src = w5; off = W_FC3; }
        else if (e < W_FC5) { src = w6; off = W_FC4; }
        else if (e < W_ME)  { src = w7; off = W_FC5; }
        else                { src = w8; off = W_ME; }
        const float4 v0 = ((const float4*)(src + (e - off)))[0];
        const float4 v1 = ((const float4*)(src + (e - off)))[1];
        bf16x8 o;
        o[0] = (__bf16)v0.x; o[1] = (__bf16)v0.y; o[2] = (__bf16)v0.z; o[3] = (__bf16)v0.w;
        o[4] = (__bf16)v1.x; o[5] = (__bf16)v1.y; o[6] = (__bf16)v1.z; o[7] = (__bf16)v1.w;
        *(bf16x8*)(wpool + (size_t)e) = o;
    } else {
        __shared__ float s[DIMD];
        for (int i = threadIdx.x; i < DIMD; i += 256) s[i] = start[i];
        __syncthreads();
        const int n = (bid - NB_BOARDS - NB_W) * 256 + threadIdx.x;
        const float4* w = (const float4*)(w1 + (size_t)n * DIMD);    // w1 = ca_w
        float acc = 0.0f;
#pragma unroll 8
        for (int k = 0; k < DIMD / 4; ++k) {
            const float4 wv = w[k];
            acc += wv.x * s[k * 4] + wv.y * s[k * 4 + 1] +
                   wv.z * s[k * 4 + 2] + wv.w * s[k * 4 + 3];
        }
        tmp[n] = acc + cab[n];
    }
}

// ---- out[b] = dot(x5[b,:512], out_w) + out_b ----
__global__ __launch_bounds__(256)
void out_head(const __bf16* __restrict__ x, const float* __restrict__ out_w,
              const float* __restrict__ out_b, float* __restrict__ out)
{
    const int wid  = threadIdx.x >> 6;
    const int lane = threadIdx.x & 63;
    const int row  = blockIdx.x * 4 + wid;
    const bf16x8 xv = *(const bf16x8*)(x + (size_t)row * DIMD + lane * 8);
    const float4 w0 = ((const float4*)out_w)[lane * 2];
    const float4 w1 = ((const float4*)out_w)[lane * 2 + 1];
    float s = (float)xv[0] * w0.x + (float)xv[1] * w0.y + (float)xv[2] * w0.z +
              (float)xv[3] * w0.w + (float)xv[4] * w1.x + (float)xv[5] * w1.y +
              (float)xv[6] * w1.z + (float)xv[7] * w1.w;
#pragma unroll
    for (int off = 32; off; off >>= 1) s += __shfl_down(s, off, 64);
    if (lane == 0) out[row] = s + out_b[0];
}

extern "C" void kernel_launch(void* const* d_in, const int* in_sizes, int n_in,
                              void* d_out, int out_size, void* d_ws, size_t ws_size,
                              hipStream_t stream)
{
    const float* boards  = (const float*)d_in[0];
    const int*   flags   = (const int*)  d_in[1];
    const int*   moves   = (const int*)  d_in[3];
    const float* start   = (const float*)d_in[4];
    const float* red_w   = (const float*)d_in[5];
    const float* red_b   = (const float*)d_in[6];
    const float* ca_w    = (const float*)d_in[7];
    const float* ca_b    = (const float*)d_in[8];
    const float* cb_w    = (const float*)d_in[9];
    const float* cb_b    = (const float*)d_in[10];
    const float* move_emb= (const float*)d_in[11];
    const float* fc1_w   = (const float*)d_in[12];
    const float* fc1_b   = (const float*)d_in[13];
    const float* fc2_w   = (const float*)d_in[14];
    const float* fc2_b   = (const float*)d_in[15];
    const float* fc3_w   = (const float*)d_in[16];
    const float* fc3_b   = (const float*)d_in[17];
    const float* fc4_w   = (const float*)d_in[18];
    const float* fc4_b   = (const float*)d_in[19];
    const float* fc5_w   = (const float*)d_in[20];
    const float* fc5_b   = (const float*)d_in[21];
    const float* out_w   = (const float*)d_in[22];
    const float* out_b   = (const float*)d_in[23];

    __bf16* wsb = (__bf16*)d_ws;
    __bf16* wpool  = wsb;                          //   3,575,808
    __bf16* b_all  = wsb + 3575808;                //  62,914,560  [81920][768]
    __bf16* e_all  = wsb + 66490368;               //  41,943,040  [81920][512]
    __bf16* eb_all = wsb + 108433408;              //  41,943,040
    __bf16* hA     = wsb + 150376448;              //   4,194,304
    __bf16* hB     = wsb + 154570752;              //   4,194,304
    float*  tmpv   = (float*)(wsb + 158765056);    //   512 f32
    __bf16* x1     = wsb + 159789056;              //   4,194,304
    __bf16* x2     = wsb + 163983360;              //   4,194,304
    __bf16* x3     = wsb + 168177664;              //   8,388,608
    __bf16* x4     = wsb + 176566272;              //   8,388,608
    __bf16* x5     = wsb + 184954880;              //   4,194,304

    const dim3 blk(256);
    const size_t LDS8P = 3 * 16384 * sizeof(__bf16);   // 96 KiB dynamic

    // fused prep: boards cvt+mask, weights cvt, start gemv
    prep<<<NB_BOARDS + NB_W + 2, blk, 0, stream>>>(
        boards, flags, b_all,
        red_w, ca_w, cb_w, fc1_w, fc2_w, fc3_w, fc4_w, fc5_w, move_emb, wpool,
        ca_b, start, tmpv);

    // batched reducer: e_all = relu(b_all @ red_w^T + red_b), 8-phase 256²
    gemm8p<1><<<dim3(2, 320), dim3(512), LDS8P, stream>>>(
        b_all, wpool + W_RED, red_b, e_all, NSTEP * BATCH, DIMD, EMBED);
    // batched eb (+ fused h1 for step-0 rows): eb_all = e_all @ cb_w^T + cb_b
    gemm256<0, true><<<dim3(4, 320), dim3(512), 0, stream>>>(
        e_all, wpool + W_CB, cb_b, tmpv, hA, eb_all,
        NSTEP * BATCH, DIMD, DIMD);

    // steps 1..9: h = tanh(h @ ca_w^T + ca_b + eb_s); BM=64 -> 512 blocks
    __bf16* hcur = hA;
    __bf16* hnxt = hB;
    for (int s = 1; s < NSTEP; ++s) {
        const __bf16* ebs = eb_all + (size_t)s * BATCH * DIMD;
        gemm_bf16<2, true, false, 64><<<dim3(4, 128), blk, 0, stream>>>(
            hcur, wpool + W_CA, ca_b, ebs, nullptr, nullptr, hnxt,
            BATCH, DIMD, DIMD);
        __bf16* t = hcur; hcur = hnxt; hnxt = t;
    }

    // MLP at BMT=128 (r15 config)
    gemm_bf16<1, false, true, 128><<<dim3(4, 64), blk, 0, stream>>>(
        hcur, wpool + W_FC1, fc1_b, nullptr, wpool + W_ME, moves, x1,
        BATCH, DIMD, DIMD + MEDIM);
    gemm_bf16<1, false, false, 128><<<dim3(4, 64), blk, 0, stream>>>(
        x1, wpool + W_FC2, fc2_b, nullptr, nullptr, nullptr, x2, BATCH, DIMD, DIMD);
    gemm_bf16<1, false, false, 128><<<dim3(8, 64), blk, 0, stream>>>(
        x2, wpool + W_FC3, fc3_b, nullptr, nullptr, nullptr, x3, BATCH, 1024, DIMD);
    gemm_bf16<1, false, false, 128><<<dim3(8, 64), blk, 0, stream>>>(
        x3, wpool + W_FC4, fc4_b, nullptr, nullptr, nullptr, x4, BATCH, 1024, 1024);
    gemm_bf16<1, false, false, 128><<<dim3(4, 64), blk, 0, stream>>>(
        x4, wpool + W_FC5, fc5_b, nullptr, nullptr, nullptr, x5, BATCH, DIMD, 1024);

    out_head<<<BATCH / 4, blk, 0, stream>>>(x5, out_w, out_b, (float*)d_out);
}